// Round 6
// baseline (173.488 us; speedup 1.0000x reference)
//
#include <hip/hip_runtime.h>
#include <hip/hip_bf16.h>

#define B_    4096
#define D_    512
#define TB_   8192        // 2B rows
#define BM    128         // block tile (2x2 waves, 64x64 per wave)
#define NTILE 64          // TB_/BM
#define NTRI  2080        // NTILE*(NTILE+1)/2 = 8*260 (XCD-bijective)
#define NH    16          // half-K-steps: D_/32
#define INV_T 14.285714285714286f   // 1/0.07

typedef __attribute__((ext_vector_type(8))) short bf16x8;
typedef __attribute__((ext_vector_type(4))) float f32x4;
typedef __attribute__((ext_vector_type(8))) unsigned short ushort8;

__device__ __forceinline__ unsigned short f2bf(float f) {
  unsigned int x = __float_as_uint(f);
  x += 0x7fffu + ((x >> 16) & 1u);   // round-to-nearest-even
  return (unsigned short)(x >> 16);
}

// ---------------------------------------------------------------------------
// Kernel 1: concat+cast fp32 -> bf16 (E[8192][512]), zero L[8192].
// ---------------------------------------------------------------------------
__global__ void ntx_prep(const float* __restrict__ a, const float* __restrict__ b,
                         unsigned short* __restrict__ E, float* __restrict__ L) {
  int t = blockIdx.x * blockDim.x + threadIdx.x;      // 0..524287
  int i = t * 8;
  const float* src = (i < B_ * D_) ? (a + i) : (b + (i - B_ * D_));
  float4 v0 = ((const float4*)src)[0];
  float4 v1 = ((const float4*)src)[1];
  ushort8 o;
  o[0] = f2bf(v0.x); o[1] = f2bf(v0.y); o[2] = f2bf(v0.z); o[3] = f2bf(v0.w);
  o[4] = f2bf(v1.x); o[5] = f2bf(v1.y); o[6] = f2bf(v1.z); o[7] = f2bf(v1.w);
  *(ushort8*)(E + i) = o;
  if (t < TB_) L[t] = 0.0f;
}

// ---------------------------------------------------------------------------
// Kernel 2: BARRIER-FREE direct-from-global register GEMM.
// No LDS, no __syncthreads/s_barrier anywhere: each wave loads its MFMA
// fragments (bf16x8 = 16B/lane) straight from L1/L2 into VGPRs. 16
// half-K-steps (K=32 each) fully unrolled, register ping-pong prefetch
// (load h+1 issued before MFMA h); compiler inserts counted vmcnt.
// Fragment layout (matches verified R2 LDS reads): row/col = lane&15,
// k = (lane>>4)*8 + j. Each wave-load touches 16 rows x 64 contiguous B
// (half a 128B line; other half consumed next half-step -> L1 reuse; the
// 2x cross-wave sharing of A (wc pair) and B (wr pair) also L1-served).
// Triangular tiles; off-diag adds mirror col-sums; pos tiles tj==ti+32.
// ---------------------------------------------------------------------------
#define LDF(buf, h)                                                              \
  do { _Pragma("unroll") for (int m = 0; m < 4; ++m)                             \
         aF[buf][m] = *(const bf16x8*)(aBase + m * (16 * D_) + (h) * 32);        \
       _Pragma("unroll") for (int n = 0; n < 4; ++n)                             \
         bF[buf][n] = *(const bf16x8*)(bBase + n * (16 * D_) + (h) * 32);        \
  } while (0)

__global__ __launch_bounds__(256, 2)
void ntx_sim(const unsigned short* __restrict__ E, float* __restrict__ L,
             float* __restrict__ pos) {
  // XCD-contiguous bijective swizzle (2080 = 8*260)
  const int bid = blockIdx.x;
  const int t   = (bid & 7) * (NTRI / 8) + (bid >> 3);
  // decode triangular index t -> (ti, tj), ti<=tj  (rows of 64 tiles)
  int ti = (int)((129.0f - sqrtf(16641.0f - 8.0f * (float)t)) * 0.5f);
  while (ti * (129 - ti) / 2 > t) --ti;
  while ((ti + 1) * (128 - ti) / 2 <= t) ++ti;
  const int tj = ti + (t - ti * (129 - ti) / 2);
  const int rowTile = ti * BM, colTile = tj * BM;
  const bool diag = (ti == tj);
  const bool posT = (tj == ti + B_ / BM);   // holds s[r][r+B] on local diag

  const int tid = threadIdx.x, lane = tid & 63, wave = tid >> 6;
  const int wr = wave >> 1, wc = wave & 1;
  const int llo = lane & 15, lhi = lane >> 4;

  // per-lane fragment base addresses (k advances by +32 elems per half-step)
  const unsigned short* aBase = E + (size_t)(rowTile + wr * 64 + llo) * D_ + lhi * 8;
  const unsigned short* bBase = E + (size_t)(colTile + wc * 64 + llo) * D_ + lhi * 8;

  f32x4 acc[4][4] = {};
  bf16x8 aF[2][4], bF[2][4];

  LDF(0, 0);
#pragma unroll
  for (int h = 0; h < NH; ++h) {
    const int cur = h & 1;
    if (h + 1 < NH) LDF(cur ^ 1, h + 1);   // prefetch next half-step
#pragma unroll
    for (int m = 0; m < 4; ++m)
#pragma unroll
      for (int n = 0; n < 4; ++n)
        acc[m][n] = __builtin_amdgcn_mfma_f32_16x16x32_bf16(aF[cur][m], bF[cur][n],
                                                            acc[m][n], 0, 0, 0);
  }

  // --- epilogue (R2-verified) ---
  // C/D layout: col = lane&15, row = (lane>>4)*4 + reg
  float cs[4] = {0.f, 0.f, 0.f, 0.f};
#pragma unroll
  for (int m = 0; m < 4; ++m) {
    float rs[4] = {0.f, 0.f, 0.f, 0.f};
#pragma unroll
    for (int n = 0; n < 4; ++n) {
      int gc = colTile + wc * 64 + n * 16 + llo;
#pragma unroll
      for (int jj = 0; jj < 4; ++jj) {
        int gr = rowTile + wr * 64 + m * 16 + lhi * 4 + jj;
        float s = acc[m][n][jj] * INV_T;
        if (posT && gc - gr == B_) pos[gr] = s;   // unique writer
        float e = __expf(s);
        e = (diag && gr == gc) ? 0.0f : e;
        rs[jj] += e;
        cs[n]  += e;
      }
    }
#pragma unroll
    for (int jj = 0; jj < 4; ++jj) {
      float v = rs[jj];
      v += __shfl_xor(v, 1);
      v += __shfl_xor(v, 2);
      v += __shfl_xor(v, 4);
      v += __shfl_xor(v, 8);
      if (llo == 0) {
        int gr = rowTile + wr * 64 + m * 16 + lhi * 4 + jj;
        atomicAdd(&L[gr], v);
      }
    }
  }
  if (!diag) {
    // column sums = row sums of mirrored tile (j,i)
#pragma unroll
    for (int n = 0; n < 4; ++n) {
      float v = cs[n];
      v += __shfl_xor(v, 16);
      v += __shfl_xor(v, 32);
      if (lhi == 0) {
        int gc = colTile + wc * 64 + n * 16 + llo;
        atomicAdd(&L[gc], v);
      }
    }
  }
}

// ---------------------------------------------------------------------------
// Kernel 3: single block: nll_r = log(L[r]) - pos[r mod B]; mean -> out.
// ---------------------------------------------------------------------------
__global__ void ntx_fin(const float* __restrict__ L, const float* __restrict__ pos,
                        float* __restrict__ out) {
  int tid = threadIdx.x;
  float s = 0.f;
#pragma unroll
  for (int k = 0; k < TB_ / 256; ++k) {
    int r = k * 256 + tid;
    s += __logf(L[r]) - pos[r & (B_ - 1)];
  }
#pragma unroll
  for (int off = 1; off < 64; off <<= 1) s += __shfl_xor(s, off);
  __shared__ float sm[4];
  if ((tid & 63) == 0) sm[tid >> 6] = s;
  __syncthreads();
  if (tid == 0) out[0] = (sm[0] + sm[1] + sm[2] + sm[3]) * (1.0f / TB_);
}

// ---------------------------------------------------------------------------
extern "C" void kernel_launch(void* const* d_in, const int* in_sizes, int n_in,
                              void* d_out, int out_size, void* d_ws, size_t ws_size,
                              hipStream_t stream) {
  const float* e1 = (const float*)d_in[0];
  const float* e2 = (const float*)d_in[1];
  float* out = (float*)d_out;
  unsigned short* E = (unsigned short*)d_ws;                        // 8 MB bf16
  float* L   = (float*)((char*)d_ws + (size_t)TB_ * D_ * 2);        // 32 KB
  float* pos = L + TB_;                                             // 16 KB

  ntx_prep<<<2048, 256, 0, stream>>>(e1, e2, E, L);
  ntx_sim<<<NTRI, 256, 0, stream>>>(E, L, pos);
  ntx_fin<<<1, 256, 0, stream>>>(L, pos, out);
}

// Round 7
// 118.803 us; speedup vs baseline: 1.4603x; 1.4603x over previous
//
#include <hip/hip_runtime.h>
#include <hip/hip_bf16.h>

#define B_    4096
#define D_    512
#define TB_   8192        // 2B rows
#define BM    128
#define BK    64
#define NK    8           // D_/BK
#define NTILE 64          // TB_/BM
#define NTRI  2080        // NTILE*(NTILE+1)/2 = 8*260 (XCD-bijective)
#define INV_T 14.285714285714286f   // 1/0.07

typedef __attribute__((ext_vector_type(8))) short bf16x8;
typedef __attribute__((ext_vector_type(4))) float f32x4;
typedef __attribute__((ext_vector_type(8))) unsigned short ushort8;

#define GLOAD_LDS16(gp, lp)                                                        \
  __builtin_amdgcn_global_load_lds((const __attribute__((address_space(1))) void*)(gp), \
                                   (__attribute__((address_space(3))) void*)(lp),  \
                                   16, 0, 0)

__device__ __forceinline__ unsigned short f2bf(float f) {
  unsigned int x = __float_as_uint(f);
  x += 0x7fffu + ((x >> 16) & 1u);   // round-to-nearest-even
  return (unsigned short)(x >> 16);
}

// ---------------------------------------------------------------------------
// Kernel 1: concat+cast fp32 -> bf16 (E[8192][512]), zero L[8192].
// ---------------------------------------------------------------------------
__global__ void ntx_prep(const float* __restrict__ a, const float* __restrict__ b,
                         unsigned short* __restrict__ E, float* __restrict__ L) {
  int t = blockIdx.x * blockDim.x + threadIdx.x;      // 0..524287
  int i = t * 8;
  const float* src = (i < B_ * D_) ? (a + i) : (b + (i - B_ * D_));
  float4 v0 = ((const float4*)src)[0];
  float4 v1 = ((const float4*)src)[1];
  ushort8 o;
  o[0] = f2bf(v0.x); o[1] = f2bf(v0.y); o[2] = f2bf(v0.z); o[3] = f2bf(v0.w);
  o[4] = f2bf(v1.x); o[5] = f2bf(v1.y); o[6] = f2bf(v1.z); o[7] = f2bf(v1.w);
  *(ushort8*)(E + i) = o;
  if (t < TB_) L[t] = 0.0f;
}

// ---------------------------------------------------------------------------
// Kernel 2: R2's proven 128x128 4-wave structure, upgraded to the T3-minimum
// pipeline: double-buffered LDS (64 KB), stage tile t+1 FIRST, then
// ds_read+MFMA tile t, then ONE __syncthreads per K-tile (its vmcnt(0)
// drain waits for loads issued ~600 cyc earlier -> latency hidden under
// MFMA instead of serially exposed twice per tile as in R2).
// Chunk-XOR swizzle (chunk ^= row&7) on BOTH global source and ds_read.
// Triangular tiles; off-diag adds mirror col-sums; pos tiles tj==ti+32.
// ---------------------------------------------------------------------------
__global__ __launch_bounds__(256, 2)
void ntx_sim(const unsigned short* __restrict__ E, float* __restrict__ L,
             float* __restrict__ pos) {
  __shared__ unsigned short As[2][BM * BK];   // 2 x 16 KB
  __shared__ unsigned short Bs[2][BM * BK];   // 2 x 16 KB

  // XCD-contiguous bijective swizzle (2080 = 8*260)
  const int bid = blockIdx.x;
  const int t   = (bid & 7) * (NTRI / 8) + (bid >> 3);
  // decode triangular index t -> (ti, tj), ti<=tj
  int ti = (int)((129.0f - sqrtf(16641.0f - 8.0f * (float)t)) * 0.5f);
  while (ti * (129 - ti) / 2 > t) --ti;
  while ((ti + 1) * (128 - ti) / 2 <= t) ++ti;
  const int tj = ti + (t - ti * (129 - ti) / 2);
  const int rowTile = ti * BM, colTile = tj * BM;
  const bool diag = (ti == tj);
  const bool posT = (tj == ti + B_ / BM);   // holds s[r][r+B] on local diag

  const int tid = threadIdx.x, lane = tid & 63, wave = tid >> 6;
  const int wr = wave >> 1, wc = wave & 1;
  const int llo = lane & 15, lhi = lane >> 4;

  // staging: tile = 128 rows x 8 chunks(16B); 4 rounds of 256 chunks.
  // source pre-swizzled (chunk ^= row&7), LDS linear (both-sides rule #21)
  unsigned offA[4], offB[4], ldsOf[4];
#pragma unroll
  for (int r = 0; r < 4; ++r) {
    int ch = r * 256 + tid, row = ch >> 3;
    int sc = ((ch & 7) ^ (row & 7)) << 3;
    offA[r]  = (unsigned)(rowTile + row) * D_ + sc;
    offB[r]  = (unsigned)(colTile + row) * D_ + sc;
    ldsOf[r] = (unsigned)ch * 8;
  }
  // fragment element-offsets within a buffer (same involution on read)
  unsigned fA[2][4], fB[2][4];
#pragma unroll
  for (int ks = 0; ks < 2; ++ks)
#pragma unroll
    for (int m = 0; m < 4; ++m) {
      int chc = ks * 4 + lhi;
      int ra  = wr * 64 + m * 16 + llo;
      fA[ks][m] = (unsigned)(ra * 8 + (chc ^ (ra & 7))) * 8;
      int rb  = wc * 64 + m * 16 + llo;
      fB[ks][m] = (unsigned)(rb * 8 + (chc ^ (rb & 7))) * 8;
    }

  // prologue: stage tile 0 -> buf 0
#pragma unroll
  for (int r = 0; r < 4; ++r) GLOAD_LDS16(E + offA[r], &As[0][ldsOf[r]]);
#pragma unroll
  for (int r = 0; r < 4; ++r) GLOAD_LDS16(E + offB[r], &Bs[0][ldsOf[r]]);
  __syncthreads();

  f32x4 acc[4][4] = {};

#pragma unroll
  for (int kt = 0; kt < NK; ++kt) {
    const int cur = kt & 1;
    // 1) issue next tile's staging FIRST (latency hides under MFMA below)
    if (kt + 1 < NK) {
      const unsigned kn = (unsigned)(kt + 1) * BK;
#pragma unroll
      for (int r = 0; r < 4; ++r) GLOAD_LDS16(E + offA[r] + kn, &As[cur ^ 1][ldsOf[r]]);
#pragma unroll
      for (int r = 0; r < 4; ++r) GLOAD_LDS16(E + offB[r] + kn, &Bs[cur ^ 1][ldsOf[r]]);
    }
    // 2) ds_read current fragments + 32 MFMA
    bf16x8 af[2][4], bf[2][4];
#pragma unroll
    for (int ks = 0; ks < 2; ++ks)
#pragma unroll
      for (int m = 0; m < 4; ++m) {
        af[ks][m] = *(const bf16x8*)&As[cur][fA[ks][m]];
        bf[ks][m] = *(const bf16x8*)&Bs[cur][fB[ks][m]];
      }
#pragma unroll
    for (int ks = 0; ks < 2; ++ks)
#pragma unroll
      for (int m = 0; m < 4; ++m)
#pragma unroll
        for (int n = 0; n < 4; ++n)
          acc[m][n] = __builtin_amdgcn_mfma_f32_16x16x32_bf16(af[ks][m], bf[ks][n],
                                                              acc[m][n], 0, 0, 0);
    // 3) one barrier per K-tile: drains the (long-issued) stage + all reads
    __syncthreads();
  }

  // --- epilogue (R2-verified) ---
  // C/D layout: col = lane&15, row = (lane>>4)*4 + reg
  float cs[4] = {0.f, 0.f, 0.f, 0.f};
#pragma unroll
  for (int m = 0; m < 4; ++m) {
    float rs[4] = {0.f, 0.f, 0.f, 0.f};
#pragma unroll
    for (int n = 0; n < 4; ++n) {
      int gc = colTile + wc * 64 + n * 16 + llo;
#pragma unroll
      for (int jj = 0; jj < 4; ++jj) {
        int gr = rowTile + wr * 64 + m * 16 + lhi * 4 + jj;
        float s = acc[m][n][jj] * INV_T;
        if (posT && gc - gr == B_) pos[gr] = s;   // unique writer
        float e = __expf(s);
        e = (diag && gr == gc) ? 0.0f : e;
        rs[jj] += e;
        cs[n]  += e;
      }
    }
#pragma unroll
    for (int jj = 0; jj < 4; ++jj) {
      float v = rs[jj];
      v += __shfl_xor(v, 1);
      v += __shfl_xor(v, 2);
      v += __shfl_xor(v, 4);
      v += __shfl_xor(v, 8);
      if (llo == 0) {
        int gr = rowTile + wr * 64 + m * 16 + lhi * 4 + jj;
        atomicAdd(&L[gr], v);
      }
    }
  }
  if (!diag) {
    // column sums = row sums of mirrored tile (j,i)
#pragma unroll
    for (int n = 0; n < 4; ++n) {
      float v = cs[n];
      v += __shfl_xor(v, 16);
      v += __shfl_xor(v, 32);
      if (lhi == 0) {
        int gc = colTile + wc * 64 + n * 16 + llo;
        atomicAdd(&L[gc], v);
      }
    }
  }
}

// ---------------------------------------------------------------------------
// Kernel 3: single block: nll_r = log(L[r]) - pos[r mod B]; mean -> out.
// ---------------------------------------------------------------------------
__global__ void ntx_fin(const float* __restrict__ L, const float* __restrict__ pos,
                        float* __restrict__ out) {
  int tid = threadIdx.x;
  float s = 0.f;
#pragma unroll
  for (int k = 0; k < TB_ / 256; ++k) {
    int r = k * 256 + tid;
    s += __logf(L[r]) - pos[r & (B_ - 1)];
  }
#pragma unroll
  for (int off = 1; off < 64; off <<= 1) s += __shfl_xor(s, off);
  __shared__ float sm[4];
  if ((tid & 63) == 0) sm[tid >> 6] = s;
  __syncthreads();
  if (tid == 0) out[0] = (sm[0] + sm[1] + sm[2] + sm[3]) * (1.0f / TB_);
}

// ---------------------------------------------------------------------------
extern "C" void kernel_launch(void* const* d_in, const int* in_sizes, int n_in,
                              void* d_out, int out_size, void* d_ws, size_t ws_size,
                              hipStream_t stream) {
  const float* e1 = (const float*)d_in[0];
  const float* e2 = (const float*)d_in[1];
  float* out = (float*)d_out;
  unsigned short* E = (unsigned short*)d_ws;                        // 8 MB bf16
  float* L   = (float*)((char*)d_ws + (size_t)TB_ * D_ * 2);        // 32 KB
  float* pos = L + TB_;                                             // 16 KB

  ntx_prep<<<2048, 256, 0, stream>>>(e1, e2, E, L);
  ntx_sim<<<NTRI, 256, 0, stream>>>(E, L, pos);
  ntx_fin<<<1, 256, 0, stream>>>(L, pos, out);
}

// Round 8
// 64.446 us; speedup vs baseline: 2.6920x; 1.8434x over previous
//
#include <hip/hip_runtime.h>
#include <hip/hip_bf16.h>

#define B_    4096
#define D_    512
#define TB_   8192        // 2B rows
#define BM    128
#define BK    64          // 64 i8 = 64 B per row per tile
#define NK    8           // D_/BK
#define NTILE 64          // TB_/BM
#define NTRI  2080        // NTILE*(NTILE+1)/2 = 8*260 (XCD-bijective)
#define INV_T 14.285714285714286f   // 1/0.07
#define SCL   (INV_T / 16129.0f)    // 1/(0.07*127*127)

typedef __attribute__((ext_vector_type(4))) int   v4i;
typedef __attribute__((ext_vector_type(4))) float f32x4;

#define GLOAD_LDS16(gp, lp)                                                        \
  __builtin_amdgcn_global_load_lds((const __attribute__((address_space(1))) void*)(gp), \
                                   (__attribute__((address_space(3))) void*)(lp),  \
                                   16, 0, 0)

// ---------------------------------------------------------------------------
// Kernel 1: concat + quantize fp32 -> int8 (E8[8192][512], q = rn(127 x)),
// zero L[8192]. 16 elems/thread.
// ---------------------------------------------------------------------------
__global__ void ntx_prep(const float* __restrict__ a, const float* __restrict__ b,
                         char* __restrict__ E8, float* __restrict__ L) {
  int t = blockIdx.x * blockDim.x + threadIdx.x;      // 0..262143
  int i = t * 16;
  const float* src = (i < B_ * D_) ? (a + i) : (b + (i - B_ * D_));
  v4i o;
#pragma unroll
  for (int g = 0; g < 4; ++g) {
    float4 v = ((const float4*)src)[g];
    int q0 = __float2int_rn(v.x * 127.0f) & 255;
    int q1 = __float2int_rn(v.y * 127.0f) & 255;
    int q2 = __float2int_rn(v.z * 127.0f) & 255;
    int q3 = __float2int_rn(v.w * 127.0f) & 255;
    o[g] = q0 | (q1 << 8) | (q2 << 16) | (q3 << 24);
  }
  ((v4i*)E8)[t] = o;
  if (t < TB_) L[t] = 0.0f;
}

// ---------------------------------------------------------------------------
// Kernel 2: R2's proven 2-barrier single-buffer 128x128 structure, int8.
// mfma_i32_16x16x64_i8: per K-tile (BK=64) ONE k-step of 16 MFMA/wave
// (vs 32 for bf16) at 2x ops/instr -> MFMA floor halves to ~6.9 us.
// LDS 16 KB total (A 8 + B 8) -> co-residency up to wave cap (8 blocks/CU).
// A/B frag: row = lane&15, k = (lane>>4)*16 + j (16 B/lane, b128 read —
// byte-identical geometry to the verified bf16 path). C/D layout is
// shape-determined (m121-128): col = lane&15, row = (lane>>4)*4 + reg.
// Chunk-XOR swizzle (chunk ^= row&3, 4 chunks/row) on BOTH source & read.
// Triangular tiles; off-diag adds mirror col-sums; pos tiles tj==ti+32.
// ---------------------------------------------------------------------------
__global__ __launch_bounds__(256, 2)
void ntx_sim(const char* __restrict__ E8, float* __restrict__ L,
             float* __restrict__ pos) {
  __shared__ __align__(16) char As[BM * BK];   // 8 KB
  __shared__ __align__(16) char Bs[BM * BK];   // 8 KB

  // XCD-contiguous bijective swizzle (2080 = 8*260)
  const int bid = blockIdx.x;
  const int t   = (bid & 7) * (NTRI / 8) + (bid >> 3);
  // decode triangular index t -> (ti, tj), ti<=tj
  int ti = (int)((129.0f - sqrtf(16641.0f - 8.0f * (float)t)) * 0.5f);
  while (ti * (129 - ti) / 2 > t) --ti;
  while ((ti + 1) * (128 - ti) / 2 <= t) ++ti;
  const int tj = ti + (t - ti * (129 - ti) / 2);
  const int rowTile = ti * BM, colTile = tj * BM;
  const bool diag = (ti == tj);
  const bool posT = (tj == ti + B_ / BM);   // holds s[r][r+B] on local diag

  const int tid = threadIdx.x, lane = tid & 63, wave = tid >> 6;
  const int wr = wave >> 1, wc = wave & 1;
  const int llo = lane & 15, lhi = lane >> 4;

  // staging: tile = 128 rows x 4 chunks(16B) = 512 chunks; 2 rounds x 256 thr.
  // source pre-swizzled (chunk ^= row&3), LDS linear (both-sides rule #21)
  unsigned offA[2], offB[2], ldsOf[2];
#pragma unroll
  for (int r = 0; r < 2; ++r) {
    int ch = r * 256 + tid, row = ch >> 2;
    int sc = ((ch & 3) ^ (row & 3)) << 4;           // byte offset in row
    offA[r]  = (unsigned)(rowTile + row) * D_ + sc;
    offB[r]  = (unsigned)(colTile + row) * D_ + sc;
    ldsOf[r] = (unsigned)ch * 16;
  }
  // fragment byte-offsets (same involution on read); 16 B per lane
  unsigned fA[4], fB[4];
#pragma unroll
  for (int m = 0; m < 4; ++m) {
    int ra = wr * 64 + m * 16 + llo;
    fA[m] = (unsigned)(ra * BK + (((unsigned)lhi ^ (ra & 3)) << 4));
    int rb = wc * 64 + m * 16 + llo;
    fB[m] = (unsigned)(rb * BK + (((unsigned)lhi ^ (rb & 3)) << 4));
  }

  v4i acc[4][4] = {};

  for (int kt = 0; kt < NK; ++kt) {
    const unsigned kb = (unsigned)kt * BK;
    // stage tile kt (A 8KB + B 8KB)
#pragma unroll
    for (int r = 0; r < 2; ++r) GLOAD_LDS16(E8 + offA[r] + kb, &As[ldsOf[r]]);
#pragma unroll
    for (int r = 0; r < 2; ++r) GLOAD_LDS16(E8 + offB[r] + kb, &Bs[ldsOf[r]]);
    __syncthreads();   // drains vmcnt: tile resident
    v4i af[4], bf[4];
#pragma unroll
    for (int m = 0; m < 4; ++m) {
      af[m] = *(const v4i*)&As[fA[m]];
      bf[m] = *(const v4i*)&Bs[fB[m]];
    }
#pragma unroll
    for (int m = 0; m < 4; ++m)
#pragma unroll
      for (int n = 0; n < 4; ++n)
        acc[m][n] = __builtin_amdgcn_mfma_i32_16x16x64_i8(af[m], bf[n],
                                                          acc[m][n], 0, 0, 0);
    __syncthreads();   // protect LDS before next staging
  }

  // --- epilogue (R2-verified, int->float scale) ---
  // C/D layout: col = lane&15, row = (lane>>4)*4 + reg
  float cs[4] = {0.f, 0.f, 0.f, 0.f};
#pragma unroll
  for (int m = 0; m < 4; ++m) {
    float rs[4] = {0.f, 0.f, 0.f, 0.f};
#pragma unroll
    for (int n = 0; n < 4; ++n) {
      int gc = colTile + wc * 64 + n * 16 + llo;
#pragma unroll
      for (int jj = 0; jj < 4; ++jj) {
        int gr = rowTile + wr * 64 + m * 16 + lhi * 4 + jj;
        float s = (float)acc[m][n][jj] * SCL;
        if (posT && gc - gr == B_) pos[gr] = s;   // unique writer
        float e = __expf(s);
        e = (diag && gr == gc) ? 0.0f : e;
        rs[jj] += e;
        cs[n]  += e;
      }
    }
#pragma unroll
    for (int jj = 0; jj < 4; ++jj) {
      float v = rs[jj];
      v += __shfl_xor(v, 1);
      v += __shfl_xor(v, 2);
      v += __shfl_xor(v, 4);
      v += __shfl_xor(v, 8);
      if (llo == 0) {
        int gr = rowTile + wr * 64 + m * 16 + lhi * 4 + jj;
        atomicAdd(&L[gr], v);
      }
    }
  }
  if (!diag) {
    // column sums = row sums of mirrored tile (j,i)
#pragma unroll
    for (int n = 0; n < 4; ++n) {
      float v = cs[n];
      v += __shfl_xor(v, 16);
      v += __shfl_xor(v, 32);
      if (lhi == 0) {
        int gc = colTile + wc * 64 + n * 16 + llo;
        atomicAdd(&L[gc], v);
      }
    }
  }
}

// ---------------------------------------------------------------------------
// Kernel 3: single block: nll_r = log(L[r]) - pos[r mod B]; mean -> out.
// ---------------------------------------------------------------------------
__global__ void ntx_fin(const float* __restrict__ L, const float* __restrict__ pos,
                        float* __restrict__ out) {
  int tid = threadIdx.x;
  float s = 0.f;
#pragma unroll
  for (int k = 0; k < TB_ / 256; ++k) {
    int r = k * 256 + tid;
    s += __logf(L[r]) - pos[r & (B_ - 1)];
  }
#pragma unroll
  for (int off = 1; off < 64; off <<= 1) s += __shfl_xor(s, off);
  __shared__ float sm[4];
  if ((tid & 63) == 0) sm[tid >> 6] = s;
  __syncthreads();
  if (tid == 0) out[0] = (sm[0] + sm[1] + sm[2] + sm[3]) * (1.0f / TB_);
}

// ---------------------------------------------------------------------------
extern "C" void kernel_launch(void* const* d_in, const int* in_sizes, int n_in,
                              void* d_out, int out_size, void* d_ws, size_t ws_size,
                              hipStream_t stream) {
  const float* e1 = (const float*)d_in[0];
  const float* e2 = (const float*)d_in[1];
  float* out = (float*)d_out;
  char* E8   = (char*)d_ws;                                        // 4 MB i8
  float* L   = (float*)((char*)d_ws + (size_t)TB_ * D_);           // 32 KB
  float* pos = L + TB_;                                            // 16 KB

  ntx_prep<<<1024, 256, 0, stream>>>(e1, e2, E8, L);
  ntx_sim<<<NTRI, 256, 0, stream>>>(E8, L, pos);
  ntx_fin<<<1, 256, 0, stream>>>(L, pos, out);
}

// Round 9
// 62.000 us; speedup vs baseline: 2.7982x; 1.0395x over previous
//
#include <hip/hip_runtime.h>
#include <hip/hip_bf16.h>

#define B_    4096
#define D_    512         // elements = bytes per row (i8)
#define TB_   8192        // 2B rows
#define BM    128
#define BK    128         // 128 i8 = 128 B per row per tile (R2 geometry)
#define NK    4           // D_/BK
#define NTILE 64          // TB_/BM
#define NTRI  2080        // NTILE*(NTILE+1)/2 = 8*260 (XCD-bijective)
#define INV_T 14.285714285714286f   // 1/0.07
#define SCL   (INV_T / 16129.0f)    // 1/(0.07*127*127)

typedef __attribute__((ext_vector_type(4))) int   v4i;

#define GLOAD_LDS16(gp, lp)                                                        \
  __builtin_amdgcn_global_load_lds((const __attribute__((address_space(1))) void*)(gp), \
                                   (__attribute__((address_space(3))) void*)(lp),  \
                                   16, 0, 0)

// ---------------------------------------------------------------------------
// Kernel 1: concat + quantize fp32 -> int8 (E8[8192][512], q = rn(127 x)),
// zero L[8192]. 16 elems/thread.
// ---------------------------------------------------------------------------
__global__ void ntx_prep(const float* __restrict__ a, const float* __restrict__ b,
                         char* __restrict__ E8, float* __restrict__ L) {
  int t = blockIdx.x * blockDim.x + threadIdx.x;      // 0..262143
  int i = t * 16;
  const float* src = (i < B_ * D_) ? (a + i) : (b + (i - B_ * D_));
  v4i o;
#pragma unroll
  for (int g = 0; g < 4; ++g) {
    float4 v = ((const float4*)src)[g];
    int q0 = __float2int_rn(v.x * 127.0f) & 255;
    int q1 = __float2int_rn(v.y * 127.0f) & 255;
    int q2 = __float2int_rn(v.z * 127.0f) & 255;
    int q3 = __float2int_rn(v.w * 127.0f) & 255;
    o[g] = q0 | (q1 << 8) | (q2 << 16) | (q3 << 24);
  }
  ((v4i*)E8)[t] = o;
  if (t < TB_) L[t] = 0.0f;
}

// ---------------------------------------------------------------------------
// Kernel 2: i8 GEMM, BK=128 (4 K-tiles): half the barrier-pairs/drains of R8.
// 128 B rows -> EXACT R2-verified addressing (8x16B chunks/row, ^row&7):
// quad = chunk^(row&7) spreads 16 rows over all 8 bank-quads, 2-way = free.
// Per K-tile: stage 16KB A + 16KB B; 2 ks-steps x 16 mfma_i32_16x16x64_i8.
// Frag: row = lane&15, k = ks*64 + (lane>>4)*16 (16 B/lane b128 read).
// C/D layout shape-determined: col = lane&15, row = (lane>>4)*4 + reg.
// Triangular tiles; off-diag adds mirror col-sums; pos tiles tj==ti+32.
// ---------------------------------------------------------------------------
__global__ __launch_bounds__(256, 2)
void ntx_sim(const char* __restrict__ E8, float* __restrict__ L,
             float* __restrict__ pos) {
  __shared__ __align__(16) char As[BM * BK];   // 16 KB
  __shared__ __align__(16) char Bs[BM * BK];   // 16 KB

  // XCD-contiguous bijective swizzle (2080 = 8*260)
  const int bid = blockIdx.x;
  const int t   = (bid & 7) * (NTRI / 8) + (bid >> 3);
  // decode triangular index t -> (ti, tj), ti<=tj
  int ti = (int)((129.0f - sqrtf(16641.0f - 8.0f * (float)t)) * 0.5f);
  while (ti * (129 - ti) / 2 > t) --ti;
  while ((ti + 1) * (128 - ti) / 2 <= t) ++ti;
  const int tj = ti + (t - ti * (129 - ti) / 2);
  const int rowTile = ti * BM, colTile = tj * BM;
  const bool diag = (ti == tj);
  const bool posT = (tj == ti + B_ / BM);   // holds s[r][r+B] on local diag

  const int tid = threadIdx.x, lane = tid & 63, wave = tid >> 6;
  const int wr = wave >> 1, wc = wave & 1;
  const int llo = lane & 15, lhi = lane >> 4;

  // staging: tile = 128 rows x 8 chunks(16B) = 1024 chunks; 4 rounds x 256 thr.
  // source pre-swizzled (chunk ^= row&7), LDS linear (both-sides rule #21)
  unsigned offA[4], offB[4], ldsOf[4];
#pragma unroll
  for (int r = 0; r < 4; ++r) {
    int ch = r * 256 + tid, row = ch >> 3;
    int sc = ((ch & 7) ^ (row & 7)) << 4;           // byte offset in row
    offA[r]  = (unsigned)(rowTile + row) * D_ + sc;
    offB[r]  = (unsigned)(colTile + row) * D_ + sc;
    ldsOf[r] = (unsigned)ch * 16;
  }
  // fragment byte-offsets (same involution on read); 16 B per lane per ks
  unsigned fA[2][4], fB[2][4];
#pragma unroll
  for (int ks = 0; ks < 2; ++ks)
#pragma unroll
    for (int m = 0; m < 4; ++m) {
      int chc = ks * 4 + lhi;
      int ra  = wr * 64 + m * 16 + llo;
      fA[ks][m] = (unsigned)(ra * BK + (((unsigned)chc ^ (ra & 7)) << 4));
      int rb  = wc * 64 + m * 16 + llo;
      fB[ks][m] = (unsigned)(rb * BK + (((unsigned)chc ^ (rb & 7)) << 4));
    }

  v4i acc[4][4] = {};

  for (int kt = 0; kt < NK; ++kt) {
    const unsigned kb = (unsigned)kt * BK;
    // stage tile kt (A 16KB + B 16KB)
#pragma unroll
    for (int r = 0; r < 4; ++r) GLOAD_LDS16(E8 + offA[r] + kb, &As[ldsOf[r]]);
#pragma unroll
    for (int r = 0; r < 4; ++r) GLOAD_LDS16(E8 + offB[r] + kb, &Bs[ldsOf[r]]);
    __syncthreads();   // drains vmcnt: tile resident
#pragma unroll
    for (int ks = 0; ks < 2; ++ks) {
      v4i af[4], bf[4];
#pragma unroll
      for (int m = 0; m < 4; ++m) {
        af[m] = *(const v4i*)&As[fA[ks][m]];
        bf[m] = *(const v4i*)&Bs[fB[ks][m]];
      }
#pragma unroll
      for (int m = 0; m < 4; ++m)
#pragma unroll
        for (int n = 0; n < 4; ++n)
          acc[m][n] = __builtin_amdgcn_mfma_i32_16x16x64_i8(af[m], bf[n],
                                                            acc[m][n], 0, 0, 0);
    }
    __syncthreads();   // protect LDS before next staging
  }

  // --- epilogue (R2-verified, int->float scale) ---
  // C/D layout: col = lane&15, row = (lane>>4)*4 + reg
  float cs[4] = {0.f, 0.f, 0.f, 0.f};
#pragma unroll
  for (int m = 0; m < 4; ++m) {
    float rs[4] = {0.f, 0.f, 0.f, 0.f};
#pragma unroll
    for (int n = 0; n < 4; ++n) {
      int gc = colTile + wc * 64 + n * 16 + llo;
#pragma unroll
      for (int jj = 0; jj < 4; ++jj) {
        int gr = rowTile + wr * 64 + m * 16 + lhi * 4 + jj;
        float s = (float)acc[m][n][jj] * SCL;
        if (posT && gc - gr == B_) pos[gr] = s;   // unique writer
        float e = __expf(s);
        e = (diag && gr == gc) ? 0.0f : e;
        rs[jj] += e;
        cs[n]  += e;
      }
    }
#pragma unroll
    for (int jj = 0; jj < 4; ++jj) {
      float v = rs[jj];
      v += __shfl_xor(v, 1);
      v += __shfl_xor(v, 2);
      v += __shfl_xor(v, 4);
      v += __shfl_xor(v, 8);
      if (llo == 0) {
        int gr = rowTile + wr * 64 + m * 16 + lhi * 4 + jj;
        atomicAdd(&L[gr], v);
      }
    }
  }
  if (!diag) {
    // column sums = row sums of mirrored tile (j,i)
#pragma unroll
    for (int n = 0; n < 4; ++n) {
      float v = cs[n];
      v += __shfl_xor(v, 16);
      v += __shfl_xor(v, 32);
      if (lhi == 0) {
        int gc = colTile + wc * 64 + n * 16 + llo;
        atomicAdd(&L[gc], v);
      }
    }
  }
}

// ---------------------------------------------------------------------------
// Kernel 3: single block: nll_r = log(L[r]) - pos[r mod B]; mean -> out.
// ---------------------------------------------------------------------------
__global__ void ntx_fin(const float* __restrict__ L, const float* __restrict__ pos,
                        float* __restrict__ out) {
  int tid = threadIdx.x;
  float s = 0.f;
#pragma unroll
  for (int k = 0; k < TB_ / 256; ++k) {
    int r = k * 256 + tid;
    s += __logf(L[r]) - pos[r & (B_ - 1)];
  }
#pragma unroll
  for (int off = 1; off < 64; off <<= 1) s += __shfl_xor(s, off);
  __shared__ float sm[4];
  if ((tid & 63) == 0) sm[tid >> 6] = s;
  __syncthreads();
  if (tid == 0) out[0] = (sm[0] + sm[1] + sm[2] + sm[3]) * (1.0f / TB_);
}

// ---------------------------------------------------------------------------
extern "C" void kernel_launch(void* const* d_in, const int* in_sizes, int n_in,
                              void* d_out, int out_size, void* d_ws, size_t ws_size,
                              hipStream_t stream) {
  const float* e1 = (const float*)d_in[0];
  const float* e2 = (const float*)d_in[1];
  float* out = (float*)d_out;
  char* E8   = (char*)d_ws;                                        // 4 MB i8
  float* L   = (float*)((char*)d_ws + (size_t)TB_ * D_);           // 32 KB
  float* pos = L + TB_;                                            // 16 KB

  ntx_prep<<<1024, 256, 0, stream>>>(e1, e2, E8, L);
  ntx_sim<<<NTRI, 256, 0, stream>>>(E8, L, pos);
  ntx_fin<<<1, 256, 0, stream>>>(L, pos, out);
}

// Round 10
// 61.653 us; speedup vs baseline: 2.8140x; 1.0056x over previous
//
#include <hip/hip_runtime.h>
#include <hip/hip_bf16.h>

#define B_    4096
#define D_    512         // elements = bytes per row (i8)
#define TB_   8192        // 2B rows
#define BM    128
#define BK    128         // 128 i8 = 128 B per row per tile (R2 geometry)
#define NK    4           // D_/BK
#define NTILE 64          // TB_/BM
#define NTRI  2080        // NTILE*(NTILE+1)/2 = 8*260 (XCD-bijective)
#define INV_T 14.285714285714286f   // 1/0.07
#define SCL   (INV_T / 16129.0f)    // 1/(0.07*127*127)

typedef __attribute__((ext_vector_type(4))) int   v4i;

#define GLOAD_LDS16(gp, lp)                                                        \
  __builtin_amdgcn_global_load_lds((const __attribute__((address_space(1))) void*)(gp), \
                                   (__attribute__((address_space(3))) void*)(lp),  \
                                   16, 0, 0)

// ---------------------------------------------------------------------------
// Kernel 1: concat + quantize fp32 -> int8 (E8[8192][512], q = rn(127 x)),
// zero L[8192]. 16 elems/thread.
// ---------------------------------------------------------------------------
__global__ void ntx_prep(const float* __restrict__ a, const float* __restrict__ b,
                         char* __restrict__ E8, float* __restrict__ L) {
  int t = blockIdx.x * blockDim.x + threadIdx.x;      // 0..262143
  int i = t * 16;
  const float* src = (i < B_ * D_) ? (a + i) : (b + (i - B_ * D_));
  v4i o;
#pragma unroll
  for (int g = 0; g < 4; ++g) {
    float4 v = ((const float4*)src)[g];
    int q0 = __float2int_rn(v.x * 127.0f) & 255;
    int q1 = __float2int_rn(v.y * 127.0f) & 255;
    int q2 = __float2int_rn(v.z * 127.0f) & 255;
    int q3 = __float2int_rn(v.w * 127.0f) & 255;
    o[g] = q0 | (q1 << 8) | (q2 << 16) | (q3 << 24);
  }
  ((v4i*)E8)[t] = o;
  if (t < TB_) L[t] = 0.0f;
}

// ---------------------------------------------------------------------------
// Kernel 2: i8 GEMM, BK=128, R9 structure UNCHANGED except
// __launch_bounds__(256, 4): forces <=128 unified regs/thread (acc 64 AGPR
// + ~60 VGPR = 124 fits) -> guaranteed 4 waves/SIMD = 4 blocks/CU
// co-resident (LDS 32KB allows 5). Doubled co-residency -> inter-block
// overlap (m114) hides stage-drain + epilogue latency chains.
// ---------------------------------------------------------------------------
__global__ __launch_bounds__(256, 4)
void ntx_sim(const char* __restrict__ E8, float* __restrict__ L,
             float* __restrict__ pos) {
  __shared__ __align__(16) char As[BM * BK];   // 16 KB
  __shared__ __align__(16) char Bs[BM * BK];   // 16 KB

  // XCD-contiguous bijective swizzle (2080 = 8*260)
  const int bid = blockIdx.x;
  const int t   = (bid & 7) * (NTRI / 8) + (bid >> 3);
  // decode triangular index t -> (ti, tj), ti<=tj
  int ti = (int)((129.0f - sqrtf(16641.0f - 8.0f * (float)t)) * 0.5f);
  while (ti * (129 - ti) / 2 > t) --ti;
  while ((ti + 1) * (128 - ti) / 2 <= t) ++ti;
  const int tj = ti + (t - ti * (129 - ti) / 2);
  const int rowTile = ti * BM, colTile = tj * BM;
  const bool diag = (ti == tj);
  const bool posT = (tj == ti + B_ / BM);   // holds s[r][r+B] on local diag

  const int tid = threadIdx.x, lane = tid & 63, wave = tid >> 6;
  const int wr = wave >> 1, wc = wave & 1;
  const int llo = lane & 15, lhi = lane >> 4;

  // staging: tile = 128 rows x 8 chunks(16B) = 1024 chunks; 4 rounds x 256 thr.
  // source pre-swizzled (chunk ^= row&7), LDS linear (both-sides rule #21)
  unsigned offA[4], offB[4], ldsOf[4];
#pragma unroll
  for (int r = 0; r < 4; ++r) {
    int ch = r * 256 + tid, row = ch >> 3;
    int sc = ((ch & 7) ^ (row & 7)) << 4;           // byte offset in row
    offA[r]  = (unsigned)(rowTile + row) * D_ + sc;
    offB[r]  = (unsigned)(colTile + row) * D_ + sc;
    ldsOf[r] = (unsigned)ch * 16;
  }
  // fragment byte-offsets (same involution on read); 16 B per lane per ks
  unsigned fA[2][4], fB[2][4];
#pragma unroll
  for (int ks = 0; ks < 2; ++ks)
#pragma unroll
    for (int m = 0; m < 4; ++m) {
      int chc = ks * 4 + lhi;
      int ra  = wr * 64 + m * 16 + llo;
      fA[ks][m] = (unsigned)(ra * BK + (((unsigned)chc ^ (ra & 7)) << 4));
      int rb  = wc * 64 + m * 16 + llo;
      fB[ks][m] = (unsigned)(rb * BK + (((unsigned)chc ^ (rb & 7)) << 4));
    }

  v4i acc[4][4] = {};

  for (int kt = 0; kt < NK; ++kt) {
    const unsigned kb = (unsigned)kt * BK;
    // stage tile kt (A 16KB + B 16KB)
#pragma unroll
    for (int r = 0; r < 4; ++r) GLOAD_LDS16(E8 + offA[r] + kb, &As[ldsOf[r]]);
#pragma unroll
    for (int r = 0; r < 4; ++r) GLOAD_LDS16(E8 + offB[r] + kb, &Bs[ldsOf[r]]);
    __syncthreads();   // drains vmcnt: tile resident
#pragma unroll
    for (int ks = 0; ks < 2; ++ks) {
      v4i af[4], bf[4];
#pragma unroll
      for (int m = 0; m < 4; ++m) {
        af[m] = *(const v4i*)&As[fA[ks][m]];
        bf[m] = *(const v4i*)&Bs[fB[ks][m]];
      }
#pragma unroll
      for (int m = 0; m < 4; ++m)
#pragma unroll
        for (int n = 0; n < 4; ++n)
          acc[m][n] = __builtin_amdgcn_mfma_i32_16x16x64_i8(af[m], bf[n],
                                                            acc[m][n], 0, 0, 0);
    }
    __syncthreads();   // protect LDS before next staging
  }

  // --- epilogue (R2-verified, int->float scale) ---
  // C/D layout: col = lane&15, row = (lane>>4)*4 + reg
  float cs[4] = {0.f, 0.f, 0.f, 0.f};
#pragma unroll
  for (int m = 0; m < 4; ++m) {
    float rs[4] = {0.f, 0.f, 0.f, 0.f};
#pragma unroll
    for (int n = 0; n < 4; ++n) {
      int gc = colTile + wc * 64 + n * 16 + llo;
#pragma unroll
      for (int jj = 0; jj < 4; ++jj) {
        int gr = rowTile + wr * 64 + m * 16 + lhi * 4 + jj;
        float s = (float)acc[m][n][jj] * SCL;
        if (posT && gc - gr == B_) pos[gr] = s;   // unique writer
        float e = __expf(s);
        e = (diag && gr == gc) ? 0.0f : e;
        rs[jj] += e;
        cs[n]  += e;
      }
    }
#pragma unroll
    for (int jj = 0; jj < 4; ++jj) {
      float v = rs[jj];
      v += __shfl_xor(v, 1);
      v += __shfl_xor(v, 2);
      v += __shfl_xor(v, 4);
      v += __shfl_xor(v, 8);
      if (llo == 0) {
        int gr = rowTile + wr * 64 + m * 16 + lhi * 4 + jj;
        atomicAdd(&L[gr], v);
      }
    }
  }
  if (!diag) {
    // column sums = row sums of mirrored tile (j,i)
#pragma unroll
    for (int n = 0; n < 4; ++n) {
      float v = cs[n];
      v += __shfl_xor(v, 16);
      v += __shfl_xor(v, 32);
      if (lhi == 0) {
        int gc = colTile + wc * 64 + n * 16 + llo;
        atomicAdd(&L[gc], v);
      }
    }
  }
}

// ---------------------------------------------------------------------------
// Kernel 3: single block: nll_r = log(L[r]) - pos[r mod B]; mean -> out.
// ---------------------------------------------------------------------------
__global__ void ntx_fin(const float* __restrict__ L, const float* __restrict__ pos,
                        float* __restrict__ out) {
  int tid = threadIdx.x;
  float s = 0.f;
#pragma unroll
  for (int k = 0; k < TB_ / 256; ++k) {
    int r = k * 256 + tid;
    s += __logf(L[r]) - pos[r & (B_ - 1)];
  }
#pragma unroll
  for (int off = 1; off < 64; off <<= 1) s += __shfl_xor(s, off);
  __shared__ float sm[4];
  if ((tid & 63) == 0) sm[tid >> 6] = s;
  __syncthreads();
  if (tid == 0) out[0] = (sm[0] + sm[1] + sm[2] + sm[3]) * (1.0f / TB_);
}

// ---------------------------------------------------------------------------
extern "C" void kernel_launch(void* const* d_in, const int* in_sizes, int n_in,
                              void* d_out, int out_size, void* d_ws, size_t ws_size,
                              hipStream_t stream) {
  const float* e1 = (const float*)d_in[0];
  const float* e2 = (const float*)d_in[1];
  float* out = (float*)d_out;
  char* E8   = (char*)d_ws;                                        // 4 MB i8
  float* L   = (float*)((char*)d_ws + (size_t)TB_ * D_);           // 32 KB
  float* pos = L + TB_;                                            // 16 KB

  ntx_prep<<<1024, 256, 0, stream>>>(e1, e2, E8, L);
  ntx_sim<<<NTRI, 256, 0, stream>>>(E8, L, pos);
  ntx_fin<<<1, 256, 0, stream>>>(L, pos, out);
}